// Round 6
// baseline (121.095 us; speedup 1.0000x reference)
//
#include <hip/hip_runtime.h>

#define B_ 4
#define S_ 512
#define T_ 512
#define D_ 256
#define NSRC (B_ * S_)            // 2048 source rows
#define K2F 2.8853900817779268f   // 2*log2(e): exp2(x*K2F) = e^(2x)

typedef __attribute__((ext_vector_type(8))) short short8;   // 8 bf16
typedef __attribute__((ext_vector_type(4))) float f32x4;
typedef __attribute__((ext_vector_type(2))) float f32x2;

__device__ __forceinline__ unsigned short f2bf(float f) {
    union { float f; unsigned u; } v; v.f = f;
    unsigned r = v.u + 0x7FFF + ((v.u >> 16) & 1);   // RNE
    return (unsigned short)(r >> 16);
}

// ---------------------------------------------------------------------------
// K1: prep (unchanged, proven). blocks 0..31: W -> WT bf16 via LDS transpose.
//     blocks 32..543: prob = softmax(target @ W_prob + b_prob).
// ---------------------------------------------------------------------------
__global__ __launch_bounds__(256) void prep_kernel(
    const float* __restrict__ tgt,
    const float* __restrict__ Wsrc, const float* __restrict__ Wtgt,
    const float* __restrict__ Wp, const float* __restrict__ bp,
    unsigned short* __restrict__ wtb, float* __restrict__ out)
{
    __shared__ float tl[64 * 65];
    const int blk = blockIdx.x, tid = threadIdx.x;

    if (blk < 32) {
        int wb = blk;
        int e = wb >> 4, ti = wb & 15, tr = ti >> 2, tc = ti & 3;
        int r0 = tr * 64, c0 = tc * 64;
        const float* W = e ? Wtgt : Wsrc;
        #pragma unroll
        for (int it = 0; it < 4; it++) {
            int rr = (tid >> 4) + it * 16;
            int cc = (tid & 15) * 4;
            float4 v = *(const float4*)&W[(r0 + rr) * D_ + c0 + cc];
            tl[(cc + 0) * 65 + rr] = v.x;
            tl[(cc + 1) * 65 + rr] = v.y;
            tl[(cc + 2) * 65 + rr] = v.z;
            tl[(cc + 3) * 65 + rr] = v.w;
        }
        __syncthreads();
        #pragma unroll
        for (int it = 0; it < 2; it++) {
            int jj = (tid >> 3) + it * 32;
            int kk = (tid & 7) * 8;
            ushort4 lo, hi;
            lo.x = f2bf(tl[jj * 65 + kk + 0]); lo.y = f2bf(tl[jj * 65 + kk + 1]);
            lo.z = f2bf(tl[jj * 65 + kk + 2]); lo.w = f2bf(tl[jj * 65 + kk + 3]);
            hi.x = f2bf(tl[jj * 65 + kk + 4]); hi.y = f2bf(tl[jj * 65 + kk + 5]);
            hi.z = f2bf(tl[jj * 65 + kk + 6]); hi.w = f2bf(tl[jj * 65 + kk + 7]);
            int idx = (e * 256 + c0 + jj) * D_ + r0 + kk;
            *(ushort4*)&wtb[idx] = lo;
            *(ushort4*)&wtb[idx + 4] = hi;
        }
    } else {
        int row  = (blk - 32) * 4 + (tid >> 6);
        int lane = tid & 63;
        float p0 = 0.f, p1 = 0.f;
        #pragma unroll
        for (int i = 0; i < 4; i++) {
            int d = lane + i * 64;
            float v = tgt[row * D_ + d];
            float2 w = *(const float2*)&Wp[d * 2];
            p0 = fmaf(v, w.x, p0);
            p1 = fmaf(v, w.y, p1);
        }
        #pragma unroll
        for (int off = 32; off > 0; off >>= 1) {
            p0 += __shfl_down(p0, off, 64);
            p1 += __shfl_down(p1, off, 64);
        }
        if (lane == 0) {
            const float L2E = 1.4426950408889634f;
            float l0 = p0 + bp[0], l1 = p1 + bp[1];
            float e10 = __builtin_amdgcn_exp2f((l1 - l0) * L2E);
            float e01 = __builtin_amdgcn_exp2f((l0 - l1) * L2E);
            out[B_ * T_ * S_ + row * 2 + 0] = __builtin_amdgcn_rcpf(1.f + e10);
            out[B_ * T_ * S_ + row * 2 + 1] = __builtin_amdgcn_rcpf(1.f + e01);
        }
    }
}

// ---------------------------------------------------------------------------
// K2: ysyt — computes Y = exp(2*(x@W+b)) for all 4096 rows.
//   s-rows (0..2047):  written TRANSPOSED  yst[d][s_global]  (for LDS staging)
//   t-rows (2048..4095): written ROW-MAJOR ytp[t_global][d]  (for SGPR loads)
//     via an LDS bounce tile (coalesced float4 stores).
// grid 256 = 64 rowblocks (64 rows) x 4 col-quarters (64 d-cols each).
// ---------------------------------------------------------------------------
__global__ __launch_bounds__(256) void ysyt_kernel(
    const float* __restrict__ src, const float* __restrict__ tgt,
    const unsigned short* __restrict__ wtb,
    const float* __restrict__ bsrc, const float* __restrict__ btgt,
    float* __restrict__ yst, float* __restrict__ ytp)
{
    __shared__ float lt[64][68];
    const int bx = blockIdx.x;
    const int rowblk = bx >> 2, colq = bx & 3;
    const int R0 = rowblk * 64;
    const int tid = threadIdx.x, lane = tid & 63, w = tid >> 6;
    const int n = lane & 15, quad = lane >> 4;
    const int mat = (R0 >= NSRC) ? 1 : 0;
    const float* bias = mat ? btgt : bsrc;
    const unsigned short* wtbase = wtb + mat * 256 * D_;
    const float* xb = mat ? &tgt[(R0 - NSRC) * D_] : &src[R0 * D_];

    short8 af[8];
    #pragma unroll
    for (int ks = 0; ks < 8; ks++) {
        const float* p = &xb[(w * 16 + n) * D_ + ks * 32 + quad * 8];
        float4 u0 = *(const float4*)p;
        float4 u1 = *(const float4*)(p + 4);
        short8 v;
        v[0] = (short)f2bf(u0.x); v[1] = (short)f2bf(u0.y);
        v[2] = (short)f2bf(u0.z); v[3] = (short)f2bf(u0.w);
        v[4] = (short)f2bf(u1.x); v[5] = (short)f2bf(u1.y);
        v[6] = (short)f2bf(u1.z); v[7] = (short)f2bf(u1.w);
        af[ks] = v;
    }

    #pragma unroll
    for (int gc = 0; gc < 4; gc++) {
        const int gcol = colq * 4 + gc;
        const unsigned short* bptr = &wtbase[(gcol * 16 + n) * D_ + quad * 8];
        short8 bf[8];
        #pragma unroll
        for (int ks = 0; ks < 8; ks++) bf[ks] = *(const short8*)&bptr[ks * 32];
        f32x4 a4 = {0.f, 0.f, 0.f, 0.f};
        #pragma unroll
        for (int ks = 0; ks < 8; ks++)
            a4 = __builtin_amdgcn_mfma_f32_16x16x32_bf16(af[ks], bf[ks], a4, 0, 0, 0);
        const float bv = bias[gcol * 16 + n];
        float4 o;
        o.x = __builtin_amdgcn_exp2f((a4[0] + bv) * K2F);
        o.y = __builtin_amdgcn_exp2f((a4[1] + bv) * K2F);
        o.z = __builtin_amdgcn_exp2f((a4[2] + bv) * K2F);
        o.w = __builtin_amdgcn_exp2f((a4[3] + bv) * K2F);
        if (mat == 0) {
            // yst[d][s_global], s_global = R0 + w*16 + quad*4 .. +3 (contiguous)
            *(float4*)&yst[(gcol * 16 + n) * NSRC + R0 + w * 16 + quad * 4] = o;
        } else {
            // bounce to LDS: lt[row_local][d_local]
            const int rl = w * 16 + quad * 4;
            const int dl = gc * 16 + n;
            lt[rl + 0][dl] = o.x;
            lt[rl + 1][dl] = o.y;
            lt[rl + 2][dl] = o.z;
            lt[rl + 3][dl] = o.w;
        }
    }
    if (mat == 1) {
        __syncthreads();
        const int row = tid >> 2, seg = tid & 3;
        const int tg = R0 - NSRC + row;            // 0..2047
        #pragma unroll
        for (int i = 0; i < 4; i++) {
            *(float4*)&ytp[tg * D_ + colq * 64 + seg * 16 + 4 * i] =
                *(const float4*)&lt[row][seg * 16 + 4 * i];
        }
    }
}

// ---------------------------------------------------------------------------
// K3: genp v2 — SGPR t-side, 4x s-read amortization.
// Tile 128s x 16t, 256 thr (4 waves), grid (4,32,4) = 512 blocks = 2 blk/CU.
// Each WAVE owns 4 consecutive t's: t-values are wave-uniform -> scalar
// s_loads from ytp[t][d] (SGPR operands, zero LDS / zero VALU broadcast cost).
// Each LANE owns 2 s (f32x2), read from lys (LDS, b64 contiguous, conflict-
// free); one s-read feeds 4 t's in registers -> LDS instrs/term cut 4x vs R5
// (0.039 -> 0.010 CU-cyc/term; VALU ~6.8us becomes the binding pipe).
// d in 4 chunks of 64, double-buffered reg->LDS staging (proven pattern).
// genP = C0 - 2 * sum_d w_d / (1 + ys*yt),  C0 = sum w + b_res.
// ---------------------------------------------------------------------------
__global__ __launch_bounds__(256) void genp_kernel(
    const float* __restrict__ yst,   // [256][2048]
    const float* __restrict__ ytp,   // [2048][256]
    const float* __restrict__ Wres, const float* __restrict__ bres,
    float* __restrict__ out)
{
    __shared__ float lys[2][64][128];   // 64 KB
    __shared__ float c0s;

    const int tid = threadIdx.x;
    const int lane = tid & 63, w = tid >> 6;
    const int s0 = blockIdx.x * 128;
    const int t0 = blockIdx.y * 16;
    const int b  = blockIdx.z;

    if (w == 0) {
        float s = Wres[lane] + Wres[lane + 64] + Wres[lane + 128] + Wres[lane + 192];
        #pragma unroll
        for (int off = 32; off > 0; off >>= 1) s += __shfl_xor(s, off, 64);
        if (lane == 0) c0s = s + bres[0];
    }

    const int wu = __builtin_amdgcn_readfirstlane(w);    // wave-uniform in SGPR
    const float* ytb0 = ytp + (b * 512 + t0 + wu * 4) * D_;  // 4 t-rows, uniform
    const int cbase = b * 512 + s0;                      // s-column base in yst

    // flat staging map: 2048 float4 per chunk; thread stages 8 consecutive
    const int sfi = tid * 8;                             // float4 index base
    const int srow = sfi >> 5;                           // 64 rows x 32 f4
    const int scol = (sfi & 31) * 4;

    // stage chunk 0 -> buf 0
    {
        #pragma unroll
        for (int j = 0; j < 8; j++) {
            const int fr = srow + ((scol + 4 * j) >> 7);
            const int fc = (scol + 4 * j) & 127;
            *(float4*)&lys[0][fr][fc] = *(const float4*)&yst[fr * NSRC + cbase + fc];
        }
    }
    __syncthreads();

    f32x2 acc[4];
    #pragma unroll
    for (int i = 0; i < 4; i++) acc[i] = (f32x2){0.f, 0.f};
    const f32x2 one2 = {1.f, 1.f};

    for (int c = 0; c < 4; c++) {
        const int bi = c & 1;
        float4 pf[8];
        if (c < 3) {
            #pragma unroll
            for (int j = 0; j < 8; j++) {
                const int fr = srow + ((scol + 4 * j) >> 7);
                const int fc = (scol + 4 * j) & 127;
                pf[j] = *(const float4*)&yst[((c + 1) * 64 + fr) * NSRC + cbase + fc];
            }
        }

        const float* wp = &Wres[c * 64];
        const float* ytb = ytb0 + c * 64;
        #pragma unroll 2
        for (int kq = 0; kq < 8; kq++) {
            const int d0 = 8 * kq;
            f32x2 ap[8];
            f32x2 wv[8];
            #pragma unroll
            for (int k = 0; k < 8; k++) {
                float2 a2 = *(const float2*)&lys[bi][d0 + k][2 * lane];
                ap[k] = (f32x2){a2.x, a2.y};
                const float wk = wp[d0 + k];             // uniform s_load
                wv[k] = (f32x2){wk, wk};
            }
            #pragma unroll
            for (int tt = 0; tt < 4; tt++) {
                const float* tp = ytb + tt * D_ + d0;    // uniform address
                float4 c0v = *(const float4*)&tp[0];     // -> s_load_dwordx4
                float4 c1v = *(const float4*)&tp[4];
                const float ctv[8] = {c0v.x, c0v.y, c0v.z, c0v.w,
                                      c1v.x, c1v.y, c1v.z, c1v.w};
                f32x2 dd[8];
                #pragma unroll
                for (int k = 0; k < 8; k++) {
                    const f32x2 cs = {ctv[k], ctv[k]};
                    dd[k] = ap[k] * cs + one2;           // 1 + ys*yt
                }
                f32x2 p01 = dd[0] * dd[1];
                f32x2 p23 = dd[2] * dd[3];
                f32x2 p45 = dd[4] * dd[5];
                f32x2 p67 = dd[6] * dd[7];
                f32x2 q03 = p01 * p23;
                f32x2 q47 = p45 * p67;
                f32x2 den = q03 * q47;
                f32x2 u01 = dd[1] * wv[0]; u01 = dd[0] * wv[1] + u01;
                f32x2 u23 = dd[3] * wv[2]; u23 = dd[2] * wv[3] + u23;
                f32x2 u45 = dd[5] * wv[4]; u45 = dd[4] * wv[5] + u45;
                f32x2 u67 = dd[7] * wv[6]; u67 = dd[6] * wv[7] + u67;
                f32x2 n03 = u01 * p23; n03 = u23 * p01 + n03;
                f32x2 n47 = u45 * p67; n47 = u67 * p45 + n47;
                f32x2 num = n03 * q47; num = n47 * q03 + num;
                f32x2 rr;
                rr.x = __builtin_amdgcn_rcpf(den.x);
                rr.y = __builtin_amdgcn_rcpf(den.y);
                acc[tt] = num * rr + acc[tt];
            }
        }

        if (c < 3) {
            #pragma unroll
            for (int j = 0; j < 8; j++) {
                const int fr = srow + ((scol + 4 * j) >> 7);
                const int fc = (scol + 4 * j) & 127;
                *(float4*)&lys[bi ^ 1][fr][fc] = pf[j];
            }
        }
        __syncthreads();
    }

    const float C0 = c0s;
    #pragma unroll
    for (int tt = 0; tt < 4; tt++) {
        float2 o;
        o.x = C0 - 2.f * acc[tt].x;
        o.y = C0 - 2.f * acc[tt].y;
        *(float2*)&out[(b * T_ + t0 + wu * 4 + tt) * S_ + s0 + 2 * lane] = o;
    }
}

extern "C" void kernel_launch(void* const* d_in, const int* in_sizes, int n_in,
                              void* d_out, int out_size, void* d_ws, size_t ws_size,
                              hipStream_t stream) {
    const float* source = (const float*)d_in[0];
    const float* target = (const float*)d_in[1];
    const float* W_src  = (const float*)d_in[2];
    const float* b_src  = (const float*)d_in[3];
    const float* W_tgt  = (const float*)d_in[4];
    const float* b_tgt  = (const float*)d_in[5];
    const float* W_res  = (const float*)d_in[6];
    const float* b_res  = (const float*)d_in[7];
    const float* W_prob = (const float*)d_in[8];
    const float* b_prob = (const float*)d_in[9];
    float* out = (float*)d_out;

    unsigned short* wtb = (unsigned short*)d_ws;          // 256 KB
    float* yst = (float*)((char*)d_ws + 256 * 1024);      // [256][2048] = 2 MB
    float* ytp = yst + 256 * NSRC;                        // [2048][256] = 2 MB

    prep_kernel<<<544, 256, 0, stream>>>(target, W_src, W_tgt,
                                         W_prob, b_prob, wtb, out);
    ysyt_kernel<<<256, 256, 0, stream>>>(source, target, wtb,
                                         b_src, b_tgt, yst, ytp);
    genp_kernel<<<dim3(4, 32, 4), 256, 0, stream>>>(yst, ytp, W_res, b_res, out);
}

// Round 7
// 109.381 us; speedup vs baseline: 1.1071x; 1.1071x over previous
//
#include <hip/hip_runtime.h>

#define B_ 4
#define S_ 512
#define T_ 512
#define D_ 256
#define NSRC (B_ * S_)            // 2048 source rows
#define NROW 4096                 // src rows + tgt rows
#define K2F 2.8853900817779268f   // 2*log2(e): exp2(x*K2F) = e^(2x)

typedef __attribute__((ext_vector_type(8))) short short8;   // 8 bf16
typedef __attribute__((ext_vector_type(4))) float f32x4;
typedef __attribute__((ext_vector_type(2))) float f32x2;

__device__ __forceinline__ unsigned short f2bf(float f) {
    union { float f; unsigned u; } v; v.f = f;
    unsigned r = v.u + 0x7FFF + ((v.u >> 16) & 1);   // RNE
    return (unsigned short)(r >> 16);
}

// ---------------------------------------------------------------------------
// K1: prep (unchanged, proven). blocks 0..31: W -> WT bf16 via LDS transpose.
//     blocks 32..543: prob = softmax(target @ W_prob + b_prob).
// ---------------------------------------------------------------------------
__global__ __launch_bounds__(256) void prep_kernel(
    const float* __restrict__ tgt,
    const float* __restrict__ Wsrc, const float* __restrict__ Wtgt,
    const float* __restrict__ Wp, const float* __restrict__ bp,
    unsigned short* __restrict__ wtb, float* __restrict__ out)
{
    __shared__ float tl[64 * 65];
    const int blk = blockIdx.x, tid = threadIdx.x;

    if (blk < 32) {
        int wb = blk;
        int e = wb >> 4, ti = wb & 15, tr = ti >> 2, tc = ti & 3;
        int r0 = tr * 64, c0 = tc * 64;
        const float* W = e ? Wtgt : Wsrc;
        #pragma unroll
        for (int it = 0; it < 4; it++) {
            int rr = (tid >> 4) + it * 16;
            int cc = (tid & 15) * 4;
            float4 v = *(const float4*)&W[(r0 + rr) * D_ + c0 + cc];
            tl[(cc + 0) * 65 + rr] = v.x;
            tl[(cc + 1) * 65 + rr] = v.y;
            tl[(cc + 2) * 65 + rr] = v.z;
            tl[(cc + 3) * 65 + rr] = v.w;
        }
        __syncthreads();
        #pragma unroll
        for (int it = 0; it < 2; it++) {
            int jj = (tid >> 3) + it * 32;
            int kk = (tid & 7) * 8;
            ushort4 lo, hi;
            lo.x = f2bf(tl[jj * 65 + kk + 0]); lo.y = f2bf(tl[jj * 65 + kk + 1]);
            lo.z = f2bf(tl[jj * 65 + kk + 2]); lo.w = f2bf(tl[jj * 65 + kk + 3]);
            hi.x = f2bf(tl[jj * 65 + kk + 4]); hi.y = f2bf(tl[jj * 65 + kk + 5]);
            hi.z = f2bf(tl[jj * 65 + kk + 6]); hi.w = f2bf(tl[jj * 65 + kk + 7]);
            int idx = (e * 256 + c0 + jj) * D_ + r0 + kk;
            *(ushort4*)&wtb[idx] = lo;
            *(ushort4*)&wtb[idx + 4] = hi;
        }
    } else {
        int row  = (blk - 32) * 4 + (tid >> 6);
        int lane = tid & 63;
        float p0 = 0.f, p1 = 0.f;
        #pragma unroll
        for (int i = 0; i < 4; i++) {
            int d = lane + i * 64;
            float v = tgt[row * D_ + d];
            float2 w = *(const float2*)&Wp[d * 2];
            p0 = fmaf(v, w.x, p0);
            p1 = fmaf(v, w.y, p1);
        }
        #pragma unroll
        for (int off = 32; off > 0; off >>= 1) {
            p0 += __shfl_down(p0, off, 64);
            p1 += __shfl_down(p1, off, 64);
        }
        if (lane == 0) {
            const float L2E = 1.4426950408889634f;
            float l0 = p0 + bp[0], l1 = p1 + bp[1];
            float e10 = __builtin_amdgcn_exp2f((l1 - l0) * L2E);
            float e01 = __builtin_amdgcn_exp2f((l0 - l1) * L2E);
            out[B_ * T_ * S_ + row * 2 + 0] = __builtin_amdgcn_rcpf(1.f + e10);
            out[B_ * T_ * S_ + row * 2 + 1] = __builtin_amdgcn_rcpf(1.f + e01);
        }
    }
}

// ---------------------------------------------------------------------------
// K2: ysyt (R5 version, proven). Y = exp(2*(x@W+b)) for all 4096 rows,
// written TRANSPOSED yst[d][global_row] (free via MFMA D-layout: each lane
// holds 4 consecutive rows at fixed d-col -> contiguous float4 store).
// grid 256 = 64 rowblocks x 4 col-quarters.
// ---------------------------------------------------------------------------
__global__ __launch_bounds__(256) void ysyt_kernel(
    const float* __restrict__ src, const float* __restrict__ tgt,
    const unsigned short* __restrict__ wtb,
    const float* __restrict__ bsrc, const float* __restrict__ btgt,
    float* __restrict__ yst)
{
    const int bx = blockIdx.x;
    const int rowblk = bx >> 2, colq = bx & 3;
    const int R0 = rowblk * 64;
    const int tid = threadIdx.x, lane = tid & 63, w = tid >> 6;
    const int n = lane & 15, quad = lane >> 4;
    const int mat = (R0 >= NSRC) ? 1 : 0;
    const float* bias = mat ? btgt : bsrc;
    const unsigned short* wtbase = wtb + mat * 256 * D_;
    const float* xb = mat ? &tgt[(R0 - NSRC) * D_] : &src[R0 * D_];

    short8 af[8];
    #pragma unroll
    for (int ks = 0; ks < 8; ks++) {
        const float* p = &xb[(w * 16 + n) * D_ + ks * 32 + quad * 8];
        float4 u0 = *(const float4*)p;
        float4 u1 = *(const float4*)(p + 4);
        short8 v;
        v[0] = (short)f2bf(u0.x); v[1] = (short)f2bf(u0.y);
        v[2] = (short)f2bf(u0.z); v[3] = (short)f2bf(u0.w);
        v[4] = (short)f2bf(u1.x); v[5] = (short)f2bf(u1.y);
        v[6] = (short)f2bf(u1.z); v[7] = (short)f2bf(u1.w);
        af[ks] = v;
    }

    #pragma unroll
    for (int gc = 0; gc < 4; gc++) {
        const int gcol = colq * 4 + gc;
        const unsigned short* bptr = &wtbase[(gcol * 16 + n) * D_ + quad * 8];
        short8 bf[8];
        #pragma unroll
        for (int ks = 0; ks < 8; ks++) bf[ks] = *(const short8*)&bptr[ks * 32];
        f32x4 a4 = {0.f, 0.f, 0.f, 0.f};
        #pragma unroll
        for (int ks = 0; ks < 8; ks++)
            a4 = __builtin_amdgcn_mfma_f32_16x16x32_bf16(af[ks], bf[ks], a4, 0, 0, 0);
        const float bv = bias[gcol * 16 + n];
        float4 o;
        o.x = __builtin_amdgcn_exp2f((a4[0] + bv) * K2F);
        o.y = __builtin_amdgcn_exp2f((a4[1] + bv) * K2F);
        o.z = __builtin_amdgcn_exp2f((a4[2] + bv) * K2F);
        o.w = __builtin_amdgcn_exp2f((a4[3] + bv) * K2F);
        *(float4*)&yst[(gcol * 16 + n) * NROW + R0 + w * 16 + quad * 4] = o;
    }
}

// ---------------------------------------------------------------------------
// K3: genp v3 — R5 skeleton, wider per-thread tile (2s x 4t).
// Tile 32s x 64t, 256 thr (4 waves), grid (16,8,4) = 512 blocks = 2 blk/CU
// (LDS 53.3KB). Per d: one ds_read_b64 (2 s) + one ds_read_b128 (4 t)
// covers 8 terms -> ~1.5x fewer LDS instrs/term than R5's 2s x 2t.
// Conflict-free by construction (R6 lesson: NO pow-2 strides):
//   lys stride 36: b64 at 2m -> 16 distinct even banks, 4-lane broadcast.
//   lyt stride 68: b128 at 4gq -> 4 distinct addrs/wave, 16-lane broadcast.
// t-component select via compile-time macro (no runtime-indexed arrays ->
// no scratch; R6's WRITE_SIZE=43MB spill tripwire watched).
// d in 4 chunks of 64, double-buffered reg->LDS staging (proven pattern).
// genP = C0 - 2 * sum_d w_d / (1 + ys*yt),  C0 = sum w + b_res.
// ---------------------------------------------------------------------------
__global__ __launch_bounds__(256) void genp_kernel(
    const float* __restrict__ yst,   // [256][4096]
    const float* __restrict__ Wres, const float* __restrict__ bres,
    float* __restrict__ out)
{
    __shared__ float lys[2][64][36];   // 18.4 KB
    __shared__ float lyt[2][64][68];   // 34.8 KB
    __shared__ float c0s;

    const int tid = threadIdx.x;
    const int lane = tid & 63, w = tid >> 6;
    const int s0 = blockIdx.x * 32;
    const int t0 = blockIdx.y * 64;
    const int b  = blockIdx.z;
    const int m  = tid & 15;           // s = s0 + 2m, 2m+1
    const int gq = tid >> 4;           // t = t0 + 4gq .. 4gq+3

    if (w == 0) {
        float s = Wres[lane] + Wres[lane + 64] + Wres[lane + 128] + Wres[lane + 192];
        #pragma unroll
        for (int off = 32; off > 0; off >>= 1) s += __shfl_xor(s, off, 64);
        if (lane == 0) c0s = s + bres[0];
    }

    const int sbase = b * S_ + s0;          // s columns in yst
    const int tbase = NSRC + b * T_ + t0;   // t columns in yst
    const int rs = tid >> 2, cs = tid & 3;  // staging: row 0..63, quarter 0..3

    // per chunk: s = 64 rows x 8 f4 (2/thread), t = 64 rows x 16 f4 (4/thread)
    float4 pf[6];
    #pragma unroll
    for (int j = 0; j < 2; j++)
        pf[j] = *(const float4*)&yst[rs * NROW + sbase + 8 * cs + 4 * j];
    #pragma unroll
    for (int j = 0; j < 4; j++)
        pf[2 + j] = *(const float4*)&yst[rs * NROW + tbase + 16 * cs + 4 * j];
    #pragma unroll
    for (int j = 0; j < 2; j++) *(float4*)&lys[0][rs][8 * cs + 4 * j] = pf[j];
    #pragma unroll
    for (int j = 0; j < 4; j++) *(float4*)&lyt[0][rs][16 * cs + 4 * j] = pf[2 + j];
    __syncthreads();

    f32x2 acc[4];
    #pragma unroll
    for (int i = 0; i < 4; i++) acc[i] = (f32x2){0.f, 0.f};
    const f32x2 one2 = {1.f, 1.f};

    for (int c = 0; c < 4; c++) {
        const int bi = c & 1;
        float4 pn[6];
        if (c < 3) {
            const int dn = (c + 1) * 64;
            #pragma unroll
            for (int j = 0; j < 2; j++)
                pn[j] = *(const float4*)&yst[(dn + rs) * NROW + sbase + 8 * cs + 4 * j];
            #pragma unroll
            for (int j = 0; j < 4; j++)
                pn[2 + j] = *(const float4*)&yst[(dn + rs) * NROW + tbase + 16 * cs + 4 * j];
        }

        const float* wp = &Wres[c * 64];
        #pragma unroll 2
        for (int kq = 0; kq < 8; kq++) {
            const int d0 = 8 * kq;
            f32x2 ap[8];
            float4 tq[8];
            f32x2 wv[8];
            #pragma unroll
            for (int k = 0; k < 8; k++) {
                float2 a2 = *(const float2*)&lys[bi][d0 + k][2 * m];
                tq[k] = *(const float4*)&lyt[bi][d0 + k][4 * gq];
                ap[k] = (f32x2){a2.x, a2.y};
                const float wk = wp[d0 + k];             // uniform s_load
                wv[k] = (f32x2){wk, wk};
            }
            // one fold per t (compile-time component select, proven math)
            #define FOLD(TT, COMP) {                                          \
                f32x2 dd[8];                                                  \
                _Pragma("unroll")                                             \
                for (int k = 0; k < 8; k++) {                                 \
                    const f32x2 cs2 = {tq[k].COMP, tq[k].COMP};               \
                    dd[k] = ap[k] * cs2 + one2;                               \
                }                                                             \
                f32x2 p01 = dd[0] * dd[1];                                    \
                f32x2 p23 = dd[2] * dd[3];                                    \
                f32x2 p45 = dd[4] * dd[5];                                    \
                f32x2 p67 = dd[6] * dd[7];                                    \
                f32x2 q03 = p01 * p23;                                        \
                f32x2 q47 = p45 * p67;                                        \
                f32x2 den = q03 * q47;                                        \
                f32x2 u01 = dd[1] * wv[0]; u01 = dd[0] * wv[1] + u01;         \
                f32x2 u23 = dd[3] * wv[2]; u23 = dd[2] * wv[3] + u23;         \
                f32x2 u45 = dd[5] * wv[4]; u45 = dd[4] * wv[5] + u45;         \
                f32x2 u67 = dd[7] * wv[6]; u67 = dd[6] * wv[7] + u67;         \
                f32x2 n03 = u01 * p23; n03 = u23 * p01 + n03;                 \
                f32x2 n47 = u45 * p67; n47 = u67 * p45 + n47;                 \
                f32x2 num = n03 * q47; num = n47 * q03 + num;                 \
                f32x2 rr;                                                     \
                rr.x = __builtin_amdgcn_rcpf(den.x);                          \
                rr.y = __builtin_amdgcn_rcpf(den.y);                          \
                acc[TT] = num * rr + acc[TT];                                 \
            }
            FOLD(0, x) FOLD(1, y) FOLD(2, z) FOLD(3, w)
            #undef FOLD
        }

        if (c < 3) {
            #pragma unroll
            for (int j = 0; j < 2; j++)
                *(float4*)&lys[bi ^ 1][rs][8 * cs + 4 * j] = pn[j];
            #pragma unroll
            for (int j = 0; j < 4; j++)
                *(float4*)&lyt[bi ^ 1][rs][16 * cs + 4 * j] = pn[2 + j];
        }
        __syncthreads();
    }

    const float C0 = c0s;
    #pragma unroll
    for (int tt = 0; tt < 4; tt++) {
        float2 o;
        o.x = C0 - 2.f * acc[tt].x;
        o.y = C0 - 2.f * acc[tt].y;
        *(float2*)&out[(b * T_ + t0 + 4 * gq + tt) * S_ + s0 + 2 * m] = o;
    }
}

extern "C" void kernel_launch(void* const* d_in, const int* in_sizes, int n_in,
                              void* d_out, int out_size, void* d_ws, size_t ws_size,
                              hipStream_t stream) {
    const float* source = (const float*)d_in[0];
    const float* target = (const float*)d_in[1];
    const float* W_src  = (const float*)d_in[2];
    const float* b_src  = (const float*)d_in[3];
    const float* W_tgt  = (const float*)d_in[4];
    const float* b_tgt  = (const float*)d_in[5];
    const float* W_res  = (const float*)d_in[6];
    const float* b_res  = (const float*)d_in[7];
    const float* W_prob = (const float*)d_in[8];
    const float* b_prob = (const float*)d_in[9];
    float* out = (float*)d_out;

    unsigned short* wtb = (unsigned short*)d_ws;          // 256 KB
    float* yst = (float*)((char*)d_ws + 256 * 1024);      // [256][4096] = 4 MB

    prep_kernel<<<544, 256, 0, stream>>>(target, W_src, W_tgt,
                                         W_prob, b_prob, wtb, out);
    ysyt_kernel<<<256, 256, 0, stream>>>(source, target, wtb,
                                         b_src, b_tgt, yst);
    genp_kernel<<<dim3(16, 8, 4), 256, 0, stream>>>(yst, W_res, b_res, out);
}

// Round 9
// 105.629 us; speedup vs baseline: 1.1464x; 1.0355x over previous
//
#include <hip/hip_runtime.h>

#define B_ 4
#define S_ 512
#define T_ 512
#define D_ 256
#define NSRC (B_ * S_)            // 2048 source rows
#define NROW 4096                 // src rows + tgt rows
#define K2F 2.8853900817779268f   // 2*log2(e): exp2(x*K2F) = e^(2x)

typedef __attribute__((ext_vector_type(8))) short short8;   // 8 bf16
typedef __attribute__((ext_vector_type(4))) float f32x4;
typedef __attribute__((ext_vector_type(2))) float f32x2;

__device__ __forceinline__ unsigned short f2bf(float f) {
    union { float f; unsigned u; } v; v.f = f;
    unsigned r = v.u + 0x7FFF + ((v.u >> 16) & 1);   // RNE
    return (unsigned short)(r >> 16);
}

// ---------------------------------------------------------------------------
// K1: ysyt+prob, 768 blocks x 256 thr.
//  blocks 0..255:  ysyt with PER-BLOCK W-slab LDS transpose (kills the prep
//    dispatch: no cross-block dep since block (rowblk,colq) only needs W
//    columns [colq*64, colq*64+64) of its mat -> 32KB bf16 slab in LDS).
//    Slab layout lwt[gc][ks][n*4+quad][8] (ushort offset
//    gc*4096 + ks*512 + n*32 + quad*8 + j) makes the B-fragment read
//    bf[ks] a contiguous b128: lane(n,quad) reads 16B at (n*4+quad)*16
//    -> 64 lanes cover 1024B linearly, conflict-free. Verified identity:
//    lwt elem = W[ks*32+quad*8+j][colq*64+gc*16+n] = WT[gcol*16+n][k]
//    == old wtb[(gcol*16+n)*D_ + ks*32+quad*8+j] read pattern.
//  blocks 256..767: prob softmax, 4 rows each (verbatim prep else-branch).
// ---------------------------------------------------------------------------
__global__ __launch_bounds__(256) void ysyt_kernel(
    const float* __restrict__ src, const float* __restrict__ tgt,
    const float* __restrict__ Wsrc, const float* __restrict__ Wtgt,
    const float* __restrict__ Wp,  const float* __restrict__ bp,
    const float* __restrict__ bsrc, const float* __restrict__ btgt,
    float* __restrict__ yst, float* __restrict__ out)
{
    __shared__ unsigned short lwt[16384];    // 32 KB
    const int bid = blockIdx.x, tid = threadIdx.x;
    const int lane = tid & 63, w = tid >> 6;

    if (bid < 256) {
        const int rowblk = bid >> 2, colq = bid & 3;
        const int R0 = rowblk * 64;
        const int n = lane & 15, quad = lane >> 4;
        const int mat = (R0 >= NSRC) ? 1 : 0;
        const float* bias = mat ? btgt : bsrc;
        const float* Wm = mat ? Wtgt : Wsrc;
        const float* xb = mat ? &tgt[(R0 - NSRC) * D_] : &src[R0 * D_];

        // ---- build W-slab transpose in LDS ----
        // thread r=tid: ksr = r>>5, qr = (r>>3)&3, jr = r&7 fixed;
        // reads W[r][colq*64 + cc], cc = 4i+c -> gc = cc>>4, nn = cc&15.
        {
            const int r = tid;
            const int ksr = r >> 5, qr = (r >> 3) & 3, jr = r & 7;
            const int wbase = ksr * 512 + qr * 8 + jr;
            #pragma unroll 4
            for (int i = 0; i < 16; i++) {
                float4 v = *(const float4*)&Wm[r * D_ + colq * 64 + 4 * i];
                const int cc = 4 * i;
                lwt[((cc + 0) >> 4) * 4096 + ((cc + 0) & 15) * 32 + wbase] = f2bf(v.x);
                lwt[((cc + 1) >> 4) * 4096 + ((cc + 1) & 15) * 32 + wbase] = f2bf(v.y);
                lwt[((cc + 2) >> 4) * 4096 + ((cc + 2) & 15) * 32 + wbase] = f2bf(v.z);
                lwt[((cc + 3) >> 4) * 4096 + ((cc + 3) & 15) * 32 + wbase] = f2bf(v.w);
            }
        }

        // ---- A fragments (verbatim) ----
        short8 af[8];
        #pragma unroll
        for (int ks = 0; ks < 8; ks++) {
            const float* p = &xb[(w * 16 + n) * D_ + ks * 32 + quad * 8];
            float4 u0 = *(const float4*)p;
            float4 u1 = *(const float4*)(p + 4);
            short8 v;
            v[0] = (short)f2bf(u0.x); v[1] = (short)f2bf(u0.y);
            v[2] = (short)f2bf(u0.z); v[3] = (short)f2bf(u0.w);
            v[4] = (short)f2bf(u1.x); v[5] = (short)f2bf(u1.y);
            v[6] = (short)f2bf(u1.z); v[7] = (short)f2bf(u1.w);
            af[ks] = v;
        }
        __syncthreads();

        // ---- MFMA + exp2 + transposed store (verbatim except B source) ----
        #pragma unroll
        for (int gc = 0; gc < 4; gc++) {
            const int gcol = colq * 4 + gc;
            const unsigned short* bp2 = &lwt[gc * 4096 + n * 32 + quad * 8];
            short8 bf[8];
            #pragma unroll
            for (int ks = 0; ks < 8; ks++) bf[ks] = *(const short8*)&bp2[ks * 512];
            f32x4 a4 = {0.f, 0.f, 0.f, 0.f};
            #pragma unroll
            for (int ks = 0; ks < 8; ks++)
                a4 = __builtin_amdgcn_mfma_f32_16x16x32_bf16(af[ks], bf[ks], a4, 0, 0, 0);
            const float bv = bias[gcol * 16 + n];
            float4 o;
            o.x = __builtin_amdgcn_exp2f((a4[0] + bv) * K2F);
            o.y = __builtin_amdgcn_exp2f((a4[1] + bv) * K2F);
            o.z = __builtin_amdgcn_exp2f((a4[2] + bv) * K2F);
            o.w = __builtin_amdgcn_exp2f((a4[3] + bv) * K2F);
            *(float4*)&yst[(gcol * 16 + n) * NROW + R0 + w * 16 + quad * 4] = o;
        }
    } else {
        // ---- prob softmax (verbatim prep else-branch) ----
        int row  = (bid - 256) * 4 + w;
        float p0 = 0.f, p1 = 0.f;
        #pragma unroll
        for (int i = 0; i < 4; i++) {
            int d = lane + i * 64;
            float v = tgt[row * D_ + d];
            float2 wv = *(const float2*)&Wp[d * 2];
            p0 = fmaf(v, wv.x, p0);
            p1 = fmaf(v, wv.y, p1);
        }
        #pragma unroll
        for (int off = 32; off > 0; off >>= 1) {
            p0 += __shfl_down(p0, off, 64);
            p1 += __shfl_down(p1, off, 64);
        }
        if (lane == 0) {
            const float L2E = 1.4426950408889634f;
            float l0 = p0 + bp[0], l1 = p1 + bp[1];
            float e10 = __builtin_amdgcn_exp2f((l1 - l0) * L2E);
            float e01 = __builtin_amdgcn_exp2f((l0 - l1) * L2E);
            out[B_ * T_ * S_ + row * 2 + 0] = __builtin_amdgcn_rcpf(1.f + e10);
            out[B_ * T_ * S_ + row * 2 + 1] = __builtin_amdgcn_rcpf(1.f + e01);
        }
    }
}

// ---------------------------------------------------------------------------
// K2: genp — VERBATIM R5 genp v1 (best measured). Tile 32s x 32t, grid
// (16,16,4) = 1024 blocks, 256 thr, 4 blocks/CU (LDS 37KB). d-chunks of 64,
// double-buffered; 2s x 2t per thread, 8-term rcp folding.
// genP = C0 - 2 * sum_d w_d / (1 + ys*yt),  C0 = sum w + b_res.
// ---------------------------------------------------------------------------
#define CLS 36
__global__ __launch_bounds__(256) void genp_kernel(
    const float* __restrict__ yst,
    const float* __restrict__ Wres, const float* __restrict__ bres,
    float* __restrict__ out)
{
    __shared__ float lys[2][64][CLS];
    __shared__ float lyt[2][64][CLS];
    __shared__ float c0s;

    const int tid = threadIdx.x;
    const int lane = tid & 63, w = tid >> 6;
    const int s0 = blockIdx.x * 32;
    const int t0 = blockIdx.y * 32;
    const int b  = blockIdx.z;
    const int m = tid & 15;            // s-pair: s0 + 2m, 2m+1
    const int g = tid >> 4;            // t-pair: t0 + 2g, 2g+1
    const int r = tid >> 3;            // staging row 0..31
    const int q = tid & 7;             // staging quad 0..7

    if (w == 0) {
        float s = Wres[lane] + Wres[lane + 64] + Wres[lane + 128] + Wres[lane + 192];
        #pragma unroll
        for (int off = 32; off > 0; off >>= 1) s += __shfl_xor(s, off, 64);
        if (lane == 0) c0s = s + bres[0];
    }

    const int ysbase = b * S_ + s0;
    const int ytbase = NSRC + b * T_ + t0;

    {
        float4 a0 = *(const float4*)&yst[(r)      * NROW + ysbase + 4 * q];
        float4 a1 = *(const float4*)&yst[(r + 32) * NROW + ysbase + 4 * q];
        float4 b0 = *(const float4*)&yst[(r)      * NROW + ytbase + 4 * q];
        float4 b1 = *(const float4*)&yst[(r + 32) * NROW + ytbase + 4 * q];
        *(float4*)&lys[0][r][4 * q]      = a0;
        *(float4*)&lys[0][r + 32][4 * q] = a1;
        *(float4*)&lyt[0][r][4 * q]      = b0;
        *(float4*)&lyt[0][r + 32][4 * q] = b1;
    }
    __syncthreads();

    f32x2 acc[2];
    acc[0] = (f32x2){0.f, 0.f};
    acc[1] = (f32x2){0.f, 0.f};
    const f32x2 one2 = {1.f, 1.f};

    for (int c = 0; c < 4; c++) {
        const int bi = c & 1;
        float4 pa0, pa1, pb0, pb1;
        if (c < 3) {
            const int dn = (c + 1) * 64;
            pa0 = *(const float4*)&yst[(dn + r)      * NROW + ysbase + 4 * q];
            pa1 = *(const float4*)&yst[(dn + r + 32) * NROW + ysbase + 4 * q];
            pb0 = *(const float4*)&yst[(dn + r)      * NROW + ytbase + 4 * q];
            pb1 = *(const float4*)&yst[(dn + r + 32) * NROW + ytbase + 4 * q];
        }

        const float* wp = &Wres[c * 64];
        #pragma unroll 2
        for (int kq = 0; kq < 8; kq++) {
            const int d0 = 8 * kq;
            f32x2 ap[8];
            float2 ct[8];
            f32x2 wv[8];
            #pragma unroll
            for (int k = 0; k < 8; k++) {
                float2 a2 = *(const float2*)&lys[bi][d0 + k][2 * m];
                ct[k] = *(const float2*)&lyt[bi][d0 + k][2 * g];
                ap[k] = (f32x2){a2.x, a2.y};
                const float wk = wp[d0 + k];     // uniform s_load
                wv[k] = (f32x2){wk, wk};
            }
            #pragma unroll
            for (int i = 0; i < 2; i++) {
                const float c0 = i ? ct[0].y : ct[0].x;
                f32x2 dd[8];
                #pragma unroll
                for (int k = 0; k < 8; k++) {
                    const float cv = i ? ct[k].y : ct[k].x;
                    const f32x2 cs = {cv, cv};
                    dd[k] = ap[k] * cs + one2;   // 1 + ys*yt
                }
                f32x2 p01 = dd[0] * dd[1];
                f32x2 p23 = dd[2] * dd[3];
                f32x2 p45 = dd[4] * dd[5];
                f32x2 p67 = dd[6] * dd[7];
                f32x2 q03 = p01 * p23;
                f32x2 q47 = p45 * p67;
                f32x2 den = q03 * q47;
                f32x2 u01 = dd[1] * wv[0]; u01 = dd[0] * wv[1] + u01;
                f32x2 u23 = dd[3] * wv[2]; u23 = dd[2] * wv[3] + u23;
                f32x2 u45 = dd[5] * wv[4]; u45 = dd[4] * wv[5] + u45;
                f32x2 u67 = dd[7] * wv[6]; u67 = dd[6] * wv[7] + u67;
                f32x2 n03 = u01 * p23; n03 = u23 * p01 + n03;
                f32x2 n47 = u45 * p67; n47 = u67 * p45 + n47;
                f32x2 num = n03 * q47; num = n47 * q03 + num;
                f32x2 rr;
                rr.x = __builtin_amdgcn_rcpf(den.x);
                rr.y = __builtin_amdgcn_rcpf(den.y);
                acc[i] = num * rr + acc[i];
                (void)c0;
            }
        }

        if (c < 3) {
            *(float4*)&lys[bi ^ 1][r][4 * q]      = pa0;
            *(float4*)&lys[bi ^ 1][r + 32][4 * q] = pa1;
            *(float4*)&lyt[bi ^ 1][r][4 * q]      = pb0;
            *(float4*)&lyt[bi ^ 1][r + 32][4 * q] = pb1;
        }
        __syncthreads();
    }

    const float C0 = c0s;
    #pragma unroll
    for (int i = 0; i < 2; i++) {
        float2 o;
        o.x = C0 - 2.f * acc[i].x;
        o.y = C0 - 2.f * acc[i].y;
        *(float2*)&out[(b * T_ + t0 + 2 * g + i) * S_ + s0 + 2 * m] = o;
    }
}

extern "C" void kernel_launch(void* const* d_in, const int* in_sizes, int n_in,
                              void* d_out, int out_size, void* d_ws, size_t ws_size,
                              hipStream_t stream) {
    const float* source = (const float*)d_in[0];
    const float* target = (const float*)d_in[1];
    const float* W_src  = (const float*)d_in[2];
    const float* b_src  = (const float*)d_in[3];
    const float* W_tgt  = (const float*)d_in[4];
    const float* b_tgt  = (const float*)d_in[5];
    const float* W_res  = (const float*)d_in[6];
    const float* b_res  = (const float*)d_in[7];
    const float* W_prob = (const float*)d_in[8];
    const float* b_prob = (const float*)d_in[9];
    float* out = (float*)d_out;

    float* yst = (float*)d_ws;                 // [256][4096] f32 = 4 MB

    ysyt_kernel<<<768, 256, 0, stream>>>(source, target, W_src, W_tgt,
                                         W_prob, b_prob, b_src, b_tgt,
                                         yst, out);
    genp_kernel<<<dim3(16, 16, 4), 256, 0, stream>>>(yst, W_res, b_res, out);
}